// Round 1
// 684.244 us; speedup vs baseline: 1.4692x; 1.4692x over previous
//
#include <hip/hip_runtime.h>
#include <stdint.h>
#include <stddef.h>

// Inputs/outputs are fp32. Weights are converted once to bf16 in ws; GEMMs run
// bf16 MFMA with fp32 accumulate.
// R1 changes vs baseline (1005 us):
//  - T2 XOR swizzle on Bs (all modes) and As (!A32): global source col pre-swizzled
//    (gl_lds dest stays linear, rule #21), ds_read applies same XOR. Kills the
//    16-way bank conflict (SQ_LDS_BANK_CONFLICT 1.68e7).
//  - T1 bijective XCD block swizzle: col-tiles sharing an A-panel land on one XCD.
//  - Batched weight conversion (1 launch instead of 17).

using u16 = unsigned short;
using u32 = unsigned int;

__device__ __forceinline__ float u2f(u16 u) {
  union { unsigned i; float f; } c; c.i = ((unsigned)u) << 16; return c.f;
}
__device__ __forceinline__ u16 f2u(float f) {
  union { float f; unsigned i; } c; c.f = f;
  unsigned u = c.i;
  u += 0x7fffu + ((u >> 16) & 1u);   // RNE to bf16
  return (u16)(u >> 16);
}
__device__ __forceinline__ u32 pk2(float lo, float hi) {
  return (u32)f2u(lo) | ((u32)f2u(hi) << 16);
}
__device__ __forceinline__ float sigm(float x) { return 1.f / (1.f + expf(-x)); }

typedef __attribute__((ext_vector_type(8))) short bfrag;   // 8 bf16 = 4 VGPRs
typedef __attribute__((ext_vector_type(4))) float f32x4;

__device__ __forceinline__ void gl_lds16(const u16* g, u16* l) {
  __builtin_amdgcn_global_load_lds((const __attribute__((address_space(1))) void*)g,
                                   (__attribute__((address_space(3))) void*)l,
                                   16, 0, 0);
}

// ---- batched fp32 -> bf16 weight conversion (17 segments, 1 launch) ----
#define NSEG 17
struct CvtArgs {
  const float* src[NSEG];
  u16* dst[NSEG];
  int cum[NSEG + 1];
};
__global__ __launch_bounds__(256) void cvt_multi(CvtArgs a, int total) {
  int i = blockIdx.x * 256 + threadIdx.x;
  if (i >= total) return;
  int s = 0;
  while (s + 1 < NSEG && i >= a.cum[s + 1]) ++s;
  const int off = i - a.cum[s];
  a.dst[s][off] = f2u(a.src[s][off]);
}

// C = epilogue(A @ W^T). A:[rows,K] row-major lda (fp32 if A32 else bf16).
// W:[cols,K] bf16 row-major ldw. rows%128==0, cols%128==0, K%64==0.
// MODE 0: outb = bf16(relu(acc + ubuf[(b*64+w)*512 + col]))   (ubuf holds bm)
// MODE 1: outb = bf16(relu(acc + bias[col]))
// MODE 2: atomicAdd(pred[row], sum_col relu(acc + bias[col]) * wlo[col])
// MODE 3: outf = acc + bias[col]      (fp32 out, direct stores)
// MODE 4: outb = bf16(relu(sigm(pred[row]) * acc + bias[col]))
// MODE 5: fused: bx<4 -> MODE0-style into outb; else W2/ldw2, MODE1-style into outb2
template <int MODE, bool A32>
__global__ __launch_bounds__(256)
void gemm_bt(const void* __restrict__ Av, int lda, size_t abase,
             const u16* __restrict__ W, int ldw, int K,
             const u16* __restrict__ bias,
             const float* __restrict__ ubuf,
             const u16* __restrict__ wlo,
             float* __restrict__ pred,
             u16* __restrict__ outb,
             float* __restrict__ outf,
             int ldc,
             const u16* __restrict__ W2, int ldw2, u16* __restrict__ outb2)
{
  // LDS: A32: As 128x72 (padded, VGPR-staged) + Bs 128x64 = 17408 u16 = 34816 B
  //      !A32: As 128x64 + Bs 128x64 (both global_load_lds, XOR-swizzled)
  // epilogue reuses smem as a 128x136 bf16 tile (17408 u16) for coalesced C writes
  __shared__ u16 smem[17408];
  constexpr int ASTR = A32 ? 72 : 64;
  u16* As = smem;
  u16* Bs = smem + (A32 ? 9216 : 8192);

  const int tid  = threadIdx.x;
  const int wave = tid >> 6, lane = tid & 63;
  const int wr = wave >> 1, wc = wave & 1;
  const int quad = lane >> 4, l16 = lane & 15;
  const int srow8 = lane >> 3;              // row within an 8-row staging chunk
  const int scol8 = (lane & 7) * 8;         // linear col elems within row
  const int scolsw = ((lane & 7) ^ srow8) * 8;  // XOR-swizzled source col (T2/m173)

  // T1: bijective XCD swizzle — consecutive work ids (which share the A row-panel
  // across col-tiles) map to the same XCD's L2 instead of round-robining.
  const int gx = gridDim.x;
  const int nwg = gx * gridDim.y;
  int flat = blockIdx.y * gx + blockIdx.x;
  if ((nwg & 7) == 0) { const int q = nwg >> 3; flat = (flat & 7) * q + (flat >> 3); }
  const int bx = flat % gx;
  const int by = flat / gx;

  const int row0 = by * 128;
  const bool isM = (MODE != 5) || (bx < 4);
  const int col0 = (MODE == 5 ? (bx & 3) : bx) * 128;
  const u16* Wp  = (MODE == 5 && !isM) ? W2  : W;
  const int ldwp = (MODE == 5 && !isM) ? ldw2 : ldw;

  f32x4 acc[4][4];
#pragma unroll
  for (int i = 0; i < 4; i++)
#pragma unroll
    for (int j = 0; j < 4; j++)
#pragma unroll
      for (int r = 0; r < 4; r++) acc[i][j][r] = 0.f;

  float4 rf[8];
  uint4  ra[4];
  if constexpr (A32) {
#pragma unroll
    for (int i = 0; i < 4; i++) {
      const int idx = i * 256 + tid, sr = idx >> 3, sc = (idx & 7) * 8;
      const float* p = (const float*)Av + (abase + (size_t)(row0 + sr)) * lda + sc;
      rf[2 * i] = *(const float4*)p;
      rf[2 * i + 1] = *(const float4*)(p + 4);
    }
#pragma unroll
    for (int i = 0; i < 4; i++) {
      ra[i].x = pk2(rf[2 * i].x, rf[2 * i].y);
      ra[i].y = pk2(rf[2 * i].z, rf[2 * i].w);
      ra[i].z = pk2(rf[2 * i + 1].x, rf[2 * i + 1].y);
      ra[i].w = pk2(rf[2 * i + 1].z, rf[2 * i + 1].w);
    }
  }

  for (int k0 = 0; k0 < K; k0 += 64) {
    __syncthreads();                     // prior tile's LDS consumers done
    if constexpr (A32) {
#pragma unroll
      for (int i = 0; i < 4; i++) {
        const int idx = i * 256 + tid, sr = idx >> 3, sc = (idx & 7) * 8;
        *(uint4*)(As + sr * ASTR + sc) = ra[i];
      }
    } else {
#pragma unroll
      for (int i = 0; i < 4; i++) {
        const int chunk = wave * 4 + i;
        // swizzled SOURCE col, linear LDS dest (gl_lds requires linear dest)
        gl_lds16((const u16*)Av + (abase + (size_t)(row0 + chunk * 8 + srow8)) * lda + k0 + scolsw,
                 As + chunk * 512 + lane * 8);
      }
    }
#pragma unroll
    for (int i = 0; i < 4; i++) {
      const int chunk = wave * 4 + i;
      gl_lds16(Wp + (size_t)(col0 + chunk * 8 + srow8) * ldwp + k0 + scolsw,
               Bs + chunk * 512 + lane * 8);
    }
    __syncthreads();                     // drains global_load_lds + ds_writes

    const bool more = (k0 + 64 < K);
    if constexpr (A32) {
      if (more) {                        // prefetch next A tile before compute
#pragma unroll
        for (int i = 0; i < 4; i++) {
          const int idx = i * 256 + tid, sr = idx >> 3, sc = (idx & 7) * 8;
          const float* p = (const float*)Av + (abase + (size_t)(row0 + sr)) * lda + (k0 + 64) + sc;
          rf[2 * i] = *(const float4*)p;
          rf[2 * i + 1] = *(const float4*)(p + 4);
        }
      }
    }

#pragma unroll
    for (int kk = 0; kk < 64; kk += 32) {
      // swizzled col-block for the b128 fragment reads (row&7 == l16&7 here)
      const int cbsw = (((kk >> 3) + quad) ^ (l16 & 7)) << 3;
      bfrag af[4], bf[4];
#pragma unroll
      for (int mt = 0; mt < 4; mt++) {
        const int R = wr * 64 + mt * 16 + l16;
        if constexpr (A32)
          af[mt] = *(const bfrag*)(As + R * ASTR + kk + quad * 8);
        else
          af[mt] = *(const bfrag*)(As + R * 64 + cbsw);
      }
#pragma unroll
      for (int nt = 0; nt < 4; nt++) {
        const int R = wc * 64 + nt * 16 + l16;
        bf[nt] = *(const bfrag*)(Bs + R * 64 + cbsw);
      }
#pragma unroll
      for (int mt = 0; mt < 4; mt++)
#pragma unroll
        for (int nt = 0; nt < 4; nt++)
          acc[mt][nt] = __builtin_amdgcn_mfma_f32_16x16x32_bf16(af[mt], bf[nt], acc[mt][nt], 0, 0, 0);
    }

    if constexpr (A32) {
      if (more) {                        // vmcnt wait lands here, after MFMAs
#pragma unroll
        for (int i = 0; i < 4; i++) {
          ra[i].x = pk2(rf[2 * i].x, rf[2 * i].y);
          ra[i].y = pk2(rf[2 * i].z, rf[2 * i].w);
          ra[i].z = pk2(rf[2 * i + 1].x, rf[2 * i + 1].y);
          ra[i].w = pk2(rf[2 * i + 1].z, rf[2 * i + 1].w);
        }
      }
    }
  }

  // C/D layout (verified m89/m91): col = lane&15, row = quad*4 + reg
  if constexpr (MODE == 2) {
#pragma unroll
    for (int mt = 0; mt < 4; mt++) {
#pragma unroll
      for (int r = 0; r < 4; r++) {
        const int rg = row0 + wr * 64 + mt * 16 + quad * 4 + r;
        float s = 0.f;
#pragma unroll
        for (int nt = 0; nt < 4; nt++) {
          const int cg = col0 + wc * 64 + nt * 16 + l16;
          float v = acc[mt][nt][r] + u2f(bias[cg]);
          v = fmaxf(v, 0.f);
          s += v * u2f(wlo[cg]);
        }
#pragma unroll
        for (int off = 1; off < 16; off <<= 1) s += __shfl_xor(s, off, 16);
        if (l16 == 0) atomicAdd(pred + rg, s);
      }
    }
  } else if constexpr (MODE == 3) {
#pragma unroll
    for (int mt = 0; mt < 4; mt++)
#pragma unroll
      for (int nt = 0; nt < 4; nt++)
#pragma unroll
        for (int r = 0; r < 4; r++) {
          const int rg = row0 + wr * 64 + mt * 16 + quad * 4 + r;
          const int cg = col0 + wc * 64 + nt * 16 + l16;
          outf[(size_t)rg * ldc + cg] = acc[mt][nt][r] + u2f(bias[cg]);
        }
  } else {
    // bf16-matrix epilogue through LDS for coalesced 16B stores
    u16* tile = smem;                    // 128 x 136
    u16* outp = (MODE == 5 && !isM) ? outb2 : outb;
    __syncthreads();                     // all waves done with As/Bs
#pragma unroll
    for (int mt = 0; mt < 4; mt++)
#pragma unroll
      for (int nt = 0; nt < 4; nt++)
#pragma unroll
        for (int r = 0; r < 4; r++) {
          const int lrow = wr * 64 + mt * 16 + quad * 4 + r;
          const int lcol = wc * 64 + nt * 16 + l16;
          const int rg = row0 + lrow;
          const int cg = col0 + lcol;
          float v = acc[mt][nt][r];
          if (MODE == 0 || (MODE == 5 && isM)) {
            const size_t grow = abase + rg;
            const int urow = (int)(((grow >> 12) << 6) | (grow & 63));   // b*64 + w
            v += ubuf[(size_t)urow * 512 + cg];
            v = fmaxf(v, 0.f);
          } else if (MODE == 1 || MODE == 5) {
            v += u2f(bias[cg]);
            v = fmaxf(v, 0.f);
          } else {  // MODE 4
            v = sigm(pred[rg]) * v + u2f(bias[cg]);
            v = fmaxf(v, 0.f);
          }
          tile[lrow * 136 + lcol] = f2u(v);
        }
    __syncthreads();
    const int row = tid >> 1, half = tid & 1;
    const u16* src = tile + row * 136 + half * 64;
    u16* dst = outp + (size_t)(row0 + row) * ldc + col0 + half * 64;
#pragma unroll
    for (int j = 0; j < 8; j++)
      *(uint4*)(dst + j * 8) = *(const uint4*)(src + j * 8);
  }
}

__global__ void fill_kernel(float* __restrict__ p, const u16* __restrict__ val, int n) {
  int i = blockIdx.x * blockDim.x + threadIdx.x;
  if (i < n) p[i] = u2f(*val);
}

__global__ void adj_out_kernel(const float* __restrict__ r, float* __restrict__ out) {
  int i = blockIdx.x * 256 + threadIdx.x;            // (b,v,w)
  int b = i >> 12, v = (i >> 6) & 63, w = i & 63;
  out[i] = r[(b << 12) + (w << 6) + v];              // pred_adj[b,v,w] = r[b,w,v]
}

__global__ __launch_bounds__(512)
void msum_kernel(const float* __restrict__ r, const u16* __restrict__ M, u16* __restrict__ x) {
  const int bv = blockIdx.x;                          // b*64+v
  const int b = bv >> 6, v = bv & 63;
  __shared__ float s[64];
  if (threadIdx.x < 64) {
    const int w = threadIdx.x;
    s[w] = sigm(r[(b << 12) + (w << 6) + v]);
  }
  __syncthreads();
  const int m = threadIdx.x;                          // channel 0..511
  const u16* Mp = M + (((size_t)(b << 12) + (v << 6)) << 9) + m;
  float acc = 0.f;
#pragma unroll 8
  for (int w = 0; w < 64; w++) acc += s[w] * u2f(Mp[(size_t)w << 9]);
  x[(size_t)bv * 512 + m] = f2u(acc);
}

__global__ __launch_bounds__(256)
void gru_kernel(const float* __restrict__ gi, const float* __restrict__ gh,
                const u16* __restrict__ h, float* __restrict__ hn) {
  int i = blockIdx.x * 256 + threadIdx.x;             // 1024*512
  int row = i >> 9, d = i & 511;
  const float* gir = gi + (size_t)row * 1536;
  const float* ghr = gh + (size_t)row * 1536;
  float rr = sigm(gir[d] + ghr[d]);
  float z  = sigm(gir[512 + d] + ghr[512 + d]);
  float n  = tanhf(gir[1024 + d] + rr * ghr[1024 + d]);
  float hv = u2f(h[i]);
  hn[i] = (1.f - z) * n + z * hv;
}

__global__ __launch_bounds__(256)
void readout_kernel(const float* __restrict__ hn,
                    const u16* __restrict__ Wr1, const u16* __restrict__ br1,
                    const u16* __restrict__ Wr2, const u16* __restrict__ br2,
                    float* __restrict__ out) {
  const int row = blockIdx.x;
  __shared__ float hrow[512];
  for (int d = threadIdx.x; d < 512; d += 256) hrow[d] = hn[(size_t)row * 512 + d];
  __syncthreads();
  const int wave = threadIdx.x >> 6, lane = threadIdx.x & 63;
  for (int j = wave; j < 28; j += 4) {
    const u16* wrow;
    float bias;
    size_t off;
    if (j < 26) { wrow = Wr1 + (size_t)j * 512; bias = u2f(br1[j]); off = 65536 + (size_t)row * 26 + j; }
    else { int jj = j - 26; wrow = Wr2 + (size_t)jj * 512; bias = u2f(br2[jj]); off = 92160 + (size_t)row * 2 + jj; }
    float s = 0.f;
    for (int d = lane; d < 512; d += 64) s += hrow[d] * u2f(wrow[d]);
#pragma unroll
    for (int o = 32; o; o >>= 1) s += __shfl_down(s, o);
    if (lane == 0) out[off] = s + bias;
  }
}

extern "C" void kernel_launch(void* const* d_in, const int* in_sizes, int n_in,
                              void* d_out, int out_size, void* d_ws, size_t ws_size,
                              hipStream_t stream)
{
  (void)in_sizes; (void)n_in; (void)out_size;
  const void*  X  = d_in[0];                 // edge_features [16,64,64,512] fp32
  char* ws = (char*)d_ws;

  const bool big = (ws_size >= 158905344ULL);   // full-H1 fused path needs ~151.5 MiB

  // ---- workspace layouts ----
  u16 *Mb, *H1, *xb, *nfb, *Wmb, *bmb, *Wl1b, *bl1b, *Wl2b, *bl2b, *Wlob, *blob;
  u16 *Wihb, *bihb, *Whhb, *bhhb, *Wr1b, *br1b, *Wr2b, *br2b;
  float *pred1, *rbuf, *ubuf, *gi, *gh, *hn;
  if (big) {
    Mb    = (u16*)(ws);                         // 64 MB  M bf16 [65536,512]
    H1    = (u16*)(ws + 67108864);              // 64 MB  link hidden, full
    pred1 = (float*)(ws + 134217728);           // 256 KB
    rbuf  = (float*)(ws + 134479872);           // 256 KB
    ubuf  = (float*)(ws + 134742016);           // 2 MB
    xb    = (u16*)(ws + 136839168);             // 1 MB
    gi    = (float*)(ws + 137887744);           // 6 MB
    gh    = (float*)(ws + 144179200);           // 6 MB
    hn    = (float*)(ws + 150470656);           // 2 MB
    nfb   = (u16*)(ws + 152567808);
    Wmb   = (u16*)(ws + 153616384);
    bmb   = (u16*)(ws + 154664960);
    Wl1b  = (u16*)(ws + 154665984);
    bl1b  = (u16*)(ws + 155190272);
    Wl2b  = (u16*)(ws + 155191296);
    bl2b  = (u16*)(ws + 155715584);
    Wlob  = (u16*)(ws + 155716608);
    blob  = (u16*)(ws + 155717632);
    Wihb  = (u16*)(ws + 155718656);
    bihb  = (u16*)(ws + 157291520);
    Whhb  = (u16*)(ws + 157295616);
    bhhb  = (u16*)(ws + 158868480);
    Wr1b  = (u16*)(ws + 158872576);
    br1b  = (u16*)(ws + 158901248);
    Wr2b  = (u16*)(ws + 158902272);
    br2b  = (u16*)(ws + 158904320);
  } else {                                      // R4 known-good quartered layout
    Mb    = (u16*)(ws);
    H1    = (u16*)(ws + 67108864);              // 16 MB quarter here
    pred1 = (float*)(ws + 83886080);
    rbuf  = (float*)(ws + 84148224);
    ubuf  = (float*)(ws + 84410368);
    xb    = (u16*)(ws + 86507520);
    gi    = (float*)(ws + 87556096);
    gh    = (float*)(ws + 93847552);
    hn    = (float*)(ws + 100139008);
    nfb   = (u16*)(ws + 102236416);
    Wmb   = (u16*)(ws + 103284992);
    bmb   = (u16*)(ws + 104333568);
    Wl1b  = (u16*)(ws + 104334592);
    bl1b  = (u16*)(ws + 104858880);
    Wl2b  = (u16*)(ws + 104859904);
    bl2b  = (u16*)(ws + 105384192);
    Wlob  = (u16*)(ws + 105385216);
    blob  = (u16*)(ws + 105386240);
    Wihb  = (u16*)(ws + 105387264);
    bihb  = (u16*)(ws + 106960128);
    Whhb  = (u16*)(ws + 106964224);
    bhhb  = (u16*)(ws + 108537088);
    Wr1b  = (u16*)(ws + 108541184);
    br1b  = (u16*)(ws + 108573952);
    Wr2b  = (u16*)(ws + 108574976);
    br2b  = (u16*)(ws + 108579072);
  }

  float* out = (float*)d_out;

  // batched weight conversion (1 launch replaces 17)
  {
    CvtArgs ca;
    const int seg_in[NSEG]  = {1,4,5,6,7,8,9,10,11,12,13,14,15,16,17,18,19};
    u16* seg_dst[NSEG] = {nfb,Wmb,bmb,Wl1b,bl1b,Wl2b,bl2b,Wlob,blob,
                          Wihb,bihb,Whhb,bhhb,Wr1b,br1b,Wr2b,br2b};
    const int seg_n[NSEG] = {524288,524288,512,262144,512,262144,512,512,1,
                             786432,1536,786432,1536,13312,26,1024,2};
    int total = 0;
    for (int s = 0; s < NSEG; s++) {
      ca.src[s] = (const float*)d_in[seg_in[s]];
      ca.dst[s] = seg_dst[s];
      ca.cum[s] = total;
      total += seg_n[s];
    }
    ca.cum[NSEG] = total;
    cvt_multi<<<(total + 255) / 256, 256, 0, stream>>>(ca, total);
  }

  // u = nf @ Wm[:, :512]^T + bm  (fp32)
  gemm_bt<3, false><<<dim3(4, 8), 256, 0, stream>>>(nfb, 512, 0, Wmb, 1024, 512, bmb,
      nullptr, nullptr, nullptr, nullptr, ubuf, 512, nullptr, 0, nullptr);
  // pred1 & rbuf (contiguous 131072 floats) = blo
  fill_kernel<<<512, 256, 0, stream>>>(pred1, blob, 131072);

  if (big) {
    // fused: [Mb | H1] = relu(X @ [Wm_e | Wl1]^T + [u | bl1]), X read once
    gemm_bt<5, true><<<dim3(8, 512), 256, 0, stream>>>(X, 512, 0, Wmb + 512, 1024, 512,
        bl1b, ubuf, nullptr, nullptr, Mb, nullptr, 512, Wl1b, 512, H1);
    // pred1 += sum relu(H1 @ Wl2^T + bl2) * Wlo
    gemm_bt<2, false><<<dim3(4, 512), 256, 0, stream>>>(H1, 512, 0, Wl2b, 512, 512, bl2b,
        nullptr, Wlob, pred1, nullptr, nullptr, 512, nullptr, 0, nullptr);
    // H1 = relu(sigm(pred1)*(X@Wm...)  -> gated link layer 1 on M
    gemm_bt<4, false><<<dim3(4, 512), 256, 0, stream>>>(Mb, 512, 0, Wl1b, 512, 512, bl1b,
        nullptr, nullptr, pred1, H1, nullptr, 512, nullptr, 0, nullptr);
    gemm_bt<2, false><<<dim3(4, 512), 256, 0, stream>>>(H1, 512, 0, Wl2b, 512, 512, bl2b,
        nullptr, Wlob, rbuf, nullptr, nullptr, 512, nullptr, 0, nullptr);
  } else {
    // M = relu(X @ Wm[:, 512:]^T + u)
    gemm_bt<0, true><<<dim3(4, 512), 256, 0, stream>>>(X, 512, 0, Wmb + 512, 1024, 512,
        nullptr, ubuf, nullptr, nullptr, Mb, nullptr, 512, nullptr, 0, nullptr);
    for (int q = 0; q < 4; q++) {
      const size_t ro = (size_t)q * 16384;
      gemm_bt<1, true><<<dim3(4, 128), 256, 0, stream>>>(X, 512, ro, Wl1b, 512, 512, bl1b,
          nullptr, nullptr, nullptr, H1, nullptr, 512, nullptr, 0, nullptr);
      gemm_bt<2, false><<<dim3(4, 128), 256, 0, stream>>>(H1, 512, 0, Wl2b, 512, 512, bl2b,
          nullptr, Wlob, pred1 + ro, nullptr, nullptr, 512, nullptr, 0, nullptr);
    }
    for (int q = 0; q < 4; q++) {
      const size_t ro = (size_t)q * 16384;
      gemm_bt<4, false><<<dim3(4, 128), 256, 0, stream>>>(Mb, 512, ro, Wl1b, 512, 512, bl1b,
          nullptr, nullptr, pred1 + ro, H1, nullptr, 512, nullptr, 0, nullptr);
      gemm_bt<2, false><<<dim3(4, 128), 256, 0, stream>>>(H1, 512, 0, Wl2b, 512, 512, bl2b,
          nullptr, Wlob, rbuf + ro, nullptr, nullptr, 512, nullptr, 0, nullptr);
    }
  }

  // pred_adj[b,v,w] = rbuf[b,w,v]
  adj_out_kernel<<<256, 256, 0, stream>>>(rbuf, out);
  // x[b,v,:] = sum_w sigmoid(rbuf[b,w,v]) * M[b,:,v,w]
  msum_kernel<<<1024, 512, 0, stream>>>(rbuf, Mb, xb);
  // GRU gates
  gemm_bt<3, false><<<dim3(12, 8), 256, 0, stream>>>(xb, 512, 0, Wihb, 512, 512, bihb,
      nullptr, nullptr, nullptr, nullptr, gi, 1536, nullptr, 0, nullptr);
  gemm_bt<3, false><<<dim3(12, 8), 256, 0, stream>>>(nfb, 512, 0, Whhb, 512, 512, bhhb,
      nullptr, nullptr, nullptr, nullptr, gh, 1536, nullptr, 0, nullptr);
  gru_kernel<<<2048, 256, 0, stream>>>(gi, gh, nfb, hn);
  readout_kernel<<<1024, 256, 0, stream>>>(hn, Wr1b, br1b, Wr2b, br2b, out);
}

// Round 2
// 661.715 us; speedup vs baseline: 1.5192x; 1.0340x over previous
//
#include <hip/hip_runtime.h>
#include <hip/hip_bf16.h>
#include <stdint.h>
#include <stddef.h>

// Inputs/outputs are fp32. Weights are converted once to bf16 in ws; GEMMs run
// bf16 MFMA with fp32 accumulate.
// R2 changes vs R1 (684 us):
//  - T3 minimum 2-phase double-buffered K-loop (m248v2 recipe): issue tile t+1
//    global_load_lds BEFORE computing tile t; ONE barrier per K-step. Hides the
//    ~900cy HBM staging latency that was fully exposed (MfmaUtil 11%).
//  - LDS 4x[128][64] bf16 XOR-swizzled buffers (64 KiB). A32 pad-72 replaced by
//    the same XOR swizzle so A/B paths unify and fit the static-LDS limit.
//  - v_cvt_pk_bf16_f32 via __float22bfloat162_rn replaces hand-rolled RNE pack
//    (~11 VALU -> 1 per pair; conversion VALU was > MFMA time in MODE5).

using u16 = unsigned short;
using u32 = unsigned int;

__device__ __forceinline__ float u2f(u16 u) {
  union { unsigned i; float f; } c; c.i = ((unsigned)u) << 16; return c.f;
}
__device__ __forceinline__ u16 f2u(float f) {
  __hip_bfloat16 h = __float2bfloat16(f);          // RNE, v_cvt_pk_bf16_f32
  union { __hip_bfloat16 h; u16 u; } c; c.h = h; return c.u;
}
__device__ __forceinline__ u32 pk2(float lo, float hi) {
  __hip_bfloat162 h = __float22bfloat162_rn(make_float2(lo, hi));
  union { __hip_bfloat162 h; u32 u; } c; c.h = h; return c.u;
}
__device__ __forceinline__ float sigm(float x) { return 1.f / (1.f + expf(-x)); }

typedef __attribute__((ext_vector_type(8))) short bfrag;   // 8 bf16 = 4 VGPRs
typedef __attribute__((ext_vector_type(4))) float f32x4;

__device__ __forceinline__ void gl_lds16(const u16* g, u16* l) {
  __builtin_amdgcn_global_load_lds((const __attribute__((address_space(1))) void*)g,
                                   (__attribute__((address_space(3))) void*)l,
                                   16, 0, 0);
}

// ---- batched fp32 -> bf16 weight conversion (17 segments, 1 launch) ----
#define NSEG 17
struct CvtArgs {
  const float* src[NSEG];
  u16* dst[NSEG];
  int cum[NSEG + 1];
};
__global__ __launch_bounds__(256) void cvt_multi(CvtArgs a, int total) {
  int i = blockIdx.x * 256 + threadIdx.x;
  if (i >= total) return;
  int s = 0;
  while (s + 1 < NSEG && i >= a.cum[s + 1]) ++s;
  const int off = i - a.cum[s];
  a.dst[s][off] = f2u(a.src[s][off]);
}

// C = epilogue(A @ W^T). A:[rows,K] row-major lda (fp32 if A32 else bf16).
// W:[cols,K] bf16 row-major ldw. rows%128==0, cols%128==0, K%64==0.
// MODE 0: outb = bf16(relu(acc + ubuf[(b*64+w)*512 + col]))   (ubuf holds bm)
// MODE 1: outb = bf16(relu(acc + bias[col]))
// MODE 2: atomicAdd(pred[row], sum_col relu(acc + bias[col]) * wlo[col])
// MODE 3: outf = acc + bias[col]      (fp32 out, direct stores)
// MODE 4: outb = bf16(relu(sigm(pred[row]) * acc + bias[col]))
// MODE 5: fused: bx<4 -> MODE0-style into outb; else W2/ldw2, MODE1-style into outb2
template <int MODE, bool A32>
__global__ __launch_bounds__(256)
void gemm_bt(const void* __restrict__ Av, int lda, size_t abase,
             const u16* __restrict__ W, int ldw, int K,
             const u16* __restrict__ bias,
             const float* __restrict__ ubuf,
             const u16* __restrict__ wlo,
             float* __restrict__ pred,
             u16* __restrict__ outb,
             float* __restrict__ outf,
             int ldc,
             const u16* __restrict__ W2, int ldw2, u16* __restrict__ outb2)
{
  // LDS: 2x As[128][64] + 2x Bs[128][64] bf16, XOR-swizzled = 32768 u16 = 64 KiB.
  // Epilogue reuses smem as a 128x136 bf16 tile (17408 u16) for coalesced stores.
  __shared__ u16 smem[32768];
  u16* const Abase = smem;
  u16* const Bbase = smem + 16384;

  const int tid  = threadIdx.x;
  const int wave = tid >> 6, lane = tid & 63;
  const int wr = wave >> 1, wc = wave & 1;
  const int quad = lane >> 4, l16 = lane & 15;
  const int srow8 = lane >> 3;              // row within an 8-row staging chunk
  const int scolsw = ((lane & 7) ^ srow8) * 8;  // XOR-swizzled source col (T2/m173)

  // T1: bijective XCD swizzle — consecutive work ids (which share the A row-panel
  // across col-tiles) map to the same XCD's L2 instead of round-robining.
  const int gx = gridDim.x;
  const int nwg = gx * gridDim.y;
  int flat = blockIdx.y * gx + blockIdx.x;
  if ((nwg & 7) == 0) { const int q = nwg >> 3; flat = (flat & 7) * q + (flat >> 3); }
  const int bx = flat % gx;
  const int by = flat / gx;

  const int row0 = by * 128;
  const bool isM = (MODE != 5) || (bx < 4);
  const int col0 = (MODE == 5 ? (bx & 3) : bx) * 128;
  const u16* Wp  = (MODE == 5 && !isM) ? W2  : W;
  const int ldwp = (MODE == 5 && !isM) ? ldw2 : ldw;

  f32x4 acc[4][4];
#pragma unroll
  for (int i = 0; i < 4; i++)
#pragma unroll
    for (int j = 0; j < 4; j++)
#pragma unroll
      for (int r = 0; r < 4; r++) acc[i][j][r] = 0.f;

  float4 rf[8];
  uint4  ra[4];

  auto stageA = [&](int kk0, u16* dst) {
#pragma unroll
    for (int i = 0; i < 4; i++) {
      const int chunk = wave * 4 + i;
      gl_lds16((const u16*)Av + (abase + (size_t)(row0 + chunk * 8 + srow8)) * lda + kk0 + scolsw,
               dst + chunk * 512 + lane * 8);
    }
  };
  auto stageB = [&](int kk0, u16* dst) {
#pragma unroll
    for (int i = 0; i < 4; i++) {
      const int chunk = wave * 4 + i;
      gl_lds16(Wp + (size_t)(col0 + chunk * 8 + srow8) * ldwp + kk0 + scolsw,
               dst + chunk * 512 + lane * 8);
    }
  };
  auto loadRF = [&](int kk0) {
#pragma unroll
    for (int i = 0; i < 4; i++) {
      const int idx = i * 256 + tid, sr = idx >> 3, sc = (idx & 7) * 8;
      const float* p = (const float*)Av + (abase + (size_t)(row0 + sr)) * lda + kk0 + sc;
      rf[2 * i]     = *(const float4*)p;
      rf[2 * i + 1] = *(const float4*)(p + 4);
    }
  };
  auto convRA = [&]() {
#pragma unroll
    for (int i = 0; i < 4; i++) {
      ra[i].x = pk2(rf[2 * i].x, rf[2 * i].y);
      ra[i].y = pk2(rf[2 * i].z, rf[2 * i].w);
      ra[i].z = pk2(rf[2 * i + 1].x, rf[2 * i + 1].y);
      ra[i].w = pk2(rf[2 * i + 1].z, rf[2 * i + 1].w);
    }
  };
  auto writeA = [&](u16* dst) {          // XOR-swizzled ds_write_b128
#pragma unroll
    for (int i = 0; i < 4; i++) {
      const int idx = i * 256 + tid, sr = idx >> 3, cb = idx & 7;
      *(uint4*)(dst + sr * 64 + ((cb ^ (sr & 7)) << 3)) = ra[i];
    }
  };
  auto compute = [&](const u16* Ac, const u16* Bc) {
#pragma unroll
    for (int kk = 0; kk < 64; kk += 32) {
      const int cb0 = (kk >> 3) + quad;
      const int cbsw = ((cb0 ^ (l16 & 7)) << 3);   // R&7 == l16&7 for all frag rows
      bfrag af[4], bf[4];
#pragma unroll
      for (int mt = 0; mt < 4; mt++) {
        const int R = wr * 64 + mt * 16 + l16;
        af[mt] = *(const bfrag*)(Ac + R * 64 + cbsw);
      }
#pragma unroll
      for (int nt2 = 0; nt2 < 4; nt2++) {
        const int R = wc * 64 + nt2 * 16 + l16;
        bf[nt2] = *(const bfrag*)(Bc + R * 64 + cbsw);
      }
#pragma unroll
      for (int mt = 0; mt < 4; mt++)
#pragma unroll
        for (int nt2 = 0; nt2 < 4; nt2++)
          acc[mt][nt2] = __builtin_amdgcn_mfma_f32_16x16x32_bf16(af[mt], bf[nt2], acc[mt][nt2], 0, 0, 0);
    }
  };

  const int ntile = K >> 6;
  int cur = 0;

  // ---- prologue: stage tile 0 ----
  if constexpr (A32) {
    loadRF(0); convRA(); writeA(Abase);
    stageB(0, Bbase);
    if (ntile > 1) loadRF(64);           // raw A of tile 1, hidden under tile 0
  } else {
    stageA(0, Abase);
    stageB(0, Bbase);
  }
  __syncthreads();                       // tile 0 ready

  // ---- T3 2-phase main loop: ONE barrier per K-step ----
  for (int t = 0; t < ntile; ++t) {
    const bool more = (t + 1 < ntile);
    u16* Ac = Abase + cur * 8192;
    u16* Bc = Bbase + cur * 8192;
    u16* An = Abase + (cur ^ 1) * 8192;
    u16* Bn = Bbase + (cur ^ 1) * 8192;
    if (more) {                          // issue next-tile loads BEFORE compute
      if constexpr (!A32) stageA((t + 1) << 6, An);
      stageB((t + 1) << 6, Bn);
    }
    compute(Ac, Bc);
    if constexpr (A32) {
      if (more) {
        convRA(); writeA(An);            // tile t+1 from rf (loaded last iter)
        if (t + 2 < ntile) loadRF((t + 2) << 6);
      }
    }
    __syncthreads();                     // drains next-tile loads; frees cur buf
    cur ^= 1;
  }

  // C/D layout (verified m89/m91): col = lane&15, row = quad*4 + reg
  if constexpr (MODE == 2) {
#pragma unroll
    for (int mt = 0; mt < 4; mt++) {
#pragma unroll
      for (int r = 0; r < 4; r++) {
        const int rg = row0 + wr * 64 + mt * 16 + quad * 4 + r;
        float s = 0.f;
#pragma unroll
        for (int nt = 0; nt < 4; nt++) {
          const int cg = col0 + wc * 64 + nt * 16 + l16;
          float v = acc[mt][nt][r] + u2f(bias[cg]);
          v = fmaxf(v, 0.f);
          s += v * u2f(wlo[cg]);
        }
#pragma unroll
        for (int off = 1; off < 16; off <<= 1) s += __shfl_xor(s, off, 16);
        if (l16 == 0) atomicAdd(pred + rg, s);
      }
    }
  } else if constexpr (MODE == 3) {
#pragma unroll
    for (int mt = 0; mt < 4; mt++)
#pragma unroll
      for (int nt = 0; nt < 4; nt++)
#pragma unroll
        for (int r = 0; r < 4; r++) {
          const int rg = row0 + wr * 64 + mt * 16 + quad * 4 + r;
          const int cg = col0 + wc * 64 + nt * 16 + l16;
          outf[(size_t)rg * ldc + cg] = acc[mt][nt][r] + u2f(bias[cg]);
        }
  } else {
    // bf16-matrix epilogue through LDS for coalesced 16B stores
    u16* tile = smem;                    // 128 x 136
    u16* outp = (MODE == 5 && !isM) ? outb2 : outb;
    __syncthreads();                     // all waves done with As/Bs
#pragma unroll
    for (int mt = 0; mt < 4; mt++)
#pragma unroll
      for (int nt = 0; nt < 4; nt++)
#pragma unroll
        for (int r = 0; r < 4; r++) {
          const int lrow = wr * 64 + mt * 16 + quad * 4 + r;
          const int lcol = wc * 64 + nt * 16 + l16;
          const int rg = row0 + lrow;
          const int cg = col0 + lcol;
          float v = acc[mt][nt][r];
          if (MODE == 0 || (MODE == 5 && isM)) {
            const size_t grow = abase + rg;
            const int urow = (int)(((grow >> 12) << 6) | (grow & 63));   // b*64 + w
            v += ubuf[(size_t)urow * 512 + cg];
            v = fmaxf(v, 0.f);
          } else if (MODE == 1 || MODE == 5) {
            v += u2f(bias[cg]);
            v = fmaxf(v, 0.f);
          } else {  // MODE 4
            v = sigm(pred[rg]) * v + u2f(bias[cg]);
            v = fmaxf(v, 0.f);
          }
          tile[lrow * 136 + lcol] = f2u(v);
        }
    __syncthreads();
    const int row = tid >> 1, half = tid & 1;
    const u16* src = tile + row * 136 + half * 64;
    u16* dst = outp + (size_t)(row0 + row) * ldc + col0 + half * 64;
#pragma unroll
    for (int j = 0; j < 8; j++)
      *(uint4*)(dst + j * 8) = *(const uint4*)(src + j * 8);
  }
}

__global__ void fill_kernel(float* __restrict__ p, const u16* __restrict__ val, int n) {
  int i = blockIdx.x * blockDim.x + threadIdx.x;
  if (i < n) p[i] = u2f(*val);
}

__global__ void adj_out_kernel(const float* __restrict__ r, float* __restrict__ out) {
  int i = blockIdx.x * 256 + threadIdx.x;            // (b,v,w)
  int b = i >> 12, v = (i >> 6) & 63, w = i & 63;
  out[i] = r[(b << 12) + (w << 6) + v];              // pred_adj[b,v,w] = r[b,w,v]
}

__global__ __launch_bounds__(512)
void msum_kernel(const float* __restrict__ r, const u16* __restrict__ M, u16* __restrict__ x) {
  const int bv = blockIdx.x;                          // b*64+v
  const int b = bv >> 6, v = bv & 63;
  __shared__ float s[64];
  if (threadIdx.x < 64) {
    const int w = threadIdx.x;
    s[w] = sigm(r[(b << 12) + (w << 6) + v]);
  }
  __syncthreads();
  const int m = threadIdx.x;                          // channel 0..511
  const u16* Mp = M + (((size_t)(b << 12) + (v << 6)) << 9) + m;
  float acc = 0.f;
#pragma unroll 8
  for (int w = 0; w < 64; w++) acc += s[w] * u2f(Mp[(size_t)w << 9]);
  x[(size_t)bv * 512 + m] = f2u(acc);
}

__global__ __launch_bounds__(256)
void gru_kernel(const float* __restrict__ gi, const float* __restrict__ gh,
                const u16* __restrict__ h, float* __restrict__ hn) {
  int i = blockIdx.x * 256 + threadIdx.x;             // 1024*512
  int row = i >> 9, d = i & 511;
  const float* gir = gi + (size_t)row * 1536;
  const float* ghr = gh + (size_t)row * 1536;
  float rr = sigm(gir[d] + ghr[d]);
  float z  = sigm(gir[512 + d] + ghr[512 + d]);
  float n  = tanhf(gir[1024 + d] + rr * ghr[1024 + d]);
  float hv = u2f(h[i]);
  hn[i] = (1.f - z) * n + z * hv;
}

__global__ __launch_bounds__(256)
void readout_kernel(const float* __restrict__ hn,
                    const u16* __restrict__ Wr1, const u16* __restrict__ br1,
                    const u16* __restrict__ Wr2, const u16* __restrict__ br2,
                    float* __restrict__ out) {
  const int row = blockIdx.x;
  __shared__ float hrow[512];
  for (int d = threadIdx.x; d < 512; d += 256) hrow[d] = hn[(size_t)row * 512 + d];
  __syncthreads();
  const int wave = threadIdx.x >> 6, lane = threadIdx.x & 63;
  for (int j = wave; j < 28; j += 4) {
    const u16* wrow;
    float bias;
    size_t off;
    if (j < 26) { wrow = Wr1 + (size_t)j * 512; bias = u2f(br1[j]); off = 65536 + (size_t)row * 26 + j; }
    else { int jj = j - 26; wrow = Wr2 + (size_t)jj * 512; bias = u2f(br2[jj]); off = 92160 + (size_t)row * 2 + jj; }
    float s = 0.f;
    for (int d = lane; d < 512; d += 64) s += hrow[d] * u2f(wrow[d]);
#pragma unroll
    for (int o = 32; o; o >>= 1) s += __shfl_down(s, o);
    if (lane == 0) out[off] = s + bias;
  }
}

extern "C" void kernel_launch(void* const* d_in, const int* in_sizes, int n_in,
                              void* d_out, int out_size, void* d_ws, size_t ws_size,
                              hipStream_t stream)
{
  (void)in_sizes; (void)n_in; (void)out_size;
  const void*  X  = d_in[0];                 // edge_features [16,64,64,512] fp32
  char* ws = (char*)d_ws;

  const bool big = (ws_size >= 158905344ULL);   // full-H1 fused path needs ~151.5 MiB

  // ---- workspace layouts ----
  u16 *Mb, *H1, *xb, *nfb, *Wmb, *bmb, *Wl1b, *bl1b, *Wl2b, *bl2b, *Wlob, *blob;
  u16 *Wihb, *bihb, *Whhb, *bhhb, *Wr1b, *br1b, *Wr2b, *br2b;
  float *pred1, *rbuf, *ubuf, *gi, *gh, *hn;
  if (big) {
    Mb    = (u16*)(ws);                         // 64 MB  M bf16 [65536,512]
    H1    = (u16*)(ws + 67108864);              // 64 MB  link hidden, full
    pred1 = (float*)(ws + 134217728);           // 256 KB
    rbuf  = (float*)(ws + 134479872);           // 256 KB
    ubuf  = (float*)(ws + 134742016);           // 2 MB
    xb    = (u16*)(ws + 136839168);             // 1 MB
    gi    = (float*)(ws + 137887744);           // 6 MB
    gh    = (float*)(ws + 144179200);           // 6 MB
    hn    = (float*)(ws + 150470656);           // 2 MB
    nfb   = (u16*)(ws + 152567808);
    Wmb   = (u16*)(ws + 153616384);
    bmb   = (u16*)(ws + 154664960);
    Wl1b  = (u16*)(ws + 154665984);
    bl1b  = (u16*)(ws + 155190272);
    Wl2b  = (u16*)(ws + 155191296);
    bl2b  = (u16*)(ws + 155715584);
    Wlob  = (u16*)(ws + 155716608);
    blob  = (u16*)(ws + 155717632);
    Wihb  = (u16*)(ws + 155718656);
    bihb  = (u16*)(ws + 157291520);
    Whhb  = (u16*)(ws + 157295616);
    bhhb  = (u16*)(ws + 158868480);
    Wr1b  = (u16*)(ws + 158872576);
    br1b  = (u16*)(ws + 158901248);
    Wr2b  = (u16*)(ws + 158902272);
    br2b  = (u16*)(ws + 158904320);
  } else {                                      // R4 known-good quartered layout
    Mb    = (u16*)(ws);
    H1    = (u16*)(ws + 67108864);              // 16 MB quarter here
    pred1 = (float*)(ws + 83886080);
    rbuf  = (float*)(ws + 84148224);
    ubuf  = (float*)(ws + 84410368);
    xb    = (u16*)(ws + 86507520);
    gi    = (float*)(ws + 87556096);
    gh    = (float*)(ws + 93847552);
    hn    = (float*)(ws + 100139008);
    nfb   = (u16*)(ws + 102236416);
    Wmb   = (u16*)(ws + 103284992);
    bmb   = (u16*)(ws + 104333568);
    Wl1b  = (u16*)(ws + 104334592);
    bl1b  = (u16*)(ws + 104858880);
    Wl2b  = (u16*)(ws + 104859904);
    bl2b  = (u16*)(ws + 105384192);
    Wlob  = (u16*)(ws + 105385216);
    blob  = (u16*)(ws + 105386240);
    Wihb  = (u16*)(ws + 105387264);
    bihb  = (u16*)(ws + 106960128);
    Whhb  = (u16*)(ws + 106964224);
    bhhb  = (u16*)(ws + 108537088);
    Wr1b  = (u16*)(ws + 108541184);
    br1b  = (u16*)(ws + 108573952);
    Wr2b  = (u16*)(ws + 108574976);
    br2b  = (u16*)(ws + 108579072);
  }

  float* out = (float*)d_out;

  // batched weight conversion (1 launch replaces 17)
  {
    CvtArgs ca;
    const int seg_in[NSEG]  = {1,4,5,6,7,8,9,10,11,12,13,14,15,16,17,18,19};
    u16* seg_dst[NSEG] = {nfb,Wmb,bmb,Wl1b,bl1b,Wl2b,bl2b,Wlob,blob,
                          Wihb,bihb,Whhb,bhhb,Wr1b,br1b,Wr2b,br2b};
    const int seg_n[NSEG] = {524288,524288,512,262144,512,262144,512,512,1,
                             786432,1536,786432,1536,13312,26,1024,2};
    int total = 0;
    for (int s = 0; s < NSEG; s++) {
      ca.src[s] = (const float*)d_in[seg_in[s]];
      ca.dst[s] = seg_dst[s];
      ca.cum[s] = total;
      total += seg_n[s];
    }
    ca.cum[NSEG] = total;
    cvt_multi<<<(total + 255) / 256, 256, 0, stream>>>(ca, total);
  }

  // u = nf @ Wm[:, :512]^T + bm  (fp32)
  gemm_bt<3, false><<<dim3(4, 8), 256, 0, stream>>>(nfb, 512, 0, Wmb, 1024, 512, bmb,
      nullptr, nullptr, nullptr, nullptr, ubuf, 512, nullptr, 0, nullptr);
  // pred1 & rbuf (contiguous 131072 floats) = blo
  fill_kernel<<<512, 256, 0, stream>>>(pred1, blob, 131072);

  if (big) {
    // fused: [Mb | H1] = relu(X @ [Wm_e | Wl1]^T + [u | bl1]), X read once
    gemm_bt<5, true><<<dim3(8, 512), 256, 0, stream>>>(X, 512, 0, Wmb + 512, 1024, 512,
        bl1b, ubuf, nullptr, nullptr, Mb, nullptr, 512, Wl1b, 512, H1);
    // pred1 += sum relu(H1 @ Wl2^T + bl2) * Wlo
    gemm_bt<2, false><<<dim3(4, 512), 256, 0, stream>>>(H1, 512, 0, Wl2b, 512, 512, bl2b,
        nullptr, Wlob, pred1, nullptr, nullptr, 512, nullptr, 0, nullptr);
    // H1 = relu(sigm(pred1)*(X@Wm...)  -> gated link layer 1 on M
    gemm_bt<4, false><<<dim3(4, 512), 256, 0, stream>>>(Mb, 512, 0, Wl1b, 512, 512, bl1b,
        nullptr, nullptr, pred1, H1, nullptr, 512, nullptr, 0, nullptr);
    gemm_bt<2, false><<<dim3(4, 512), 256, 0, stream>>>(H1, 512, 0, Wl2b, 512, 512, bl2b,
        nullptr, Wlob, rbuf, nullptr, nullptr, 512, nullptr, 0, nullptr);
  } else {
    // M = relu(X @ Wm[:, 512:]^T + u)
    gemm_bt<0, true><<<dim3(4, 512), 256, 0, stream>>>(X, 512, 0, Wmb + 512, 1024, 512,
        nullptr, ubuf, nullptr, nullptr, Mb, nullptr, 512, nullptr, 0, nullptr);
    for (int q = 0; q < 4; q++) {
      const size_t ro = (size_t)q * 16384;
      gemm_bt<1, true><<<dim3(4, 128), 256, 0, stream>>>(X, 512, ro, Wl1b, 512, 512, bl1b,
          nullptr, nullptr, nullptr, H1, nullptr, 512, nullptr, 0, nullptr);
      gemm_bt<2, false><<<dim3(4, 128), 256, 0, stream>>>(H1, 512, 0, Wl2b, 512, 512, bl2b,
          nullptr, Wlob, pred1 + ro, nullptr, nullptr, 512, nullptr, 0, nullptr);
    }
    for (int q = 0; q < 4; q++) {
      const size_t ro = (size_t)q * 16384;
      gemm_bt<4, false><<<dim3(4, 128), 256, 0, stream>>>(Mb, 512, ro, Wl1b, 512, 512, bl1b,
          nullptr, nullptr, pred1 + ro, H1, nullptr, 512, nullptr, 0, nullptr);
      gemm_bt<2, false><<<dim3(4, 128), 256, 0, stream>>>(H1, 512, 0, Wl2b, 512, 512, bl2b,
          nullptr, Wlob, rbuf + ro, nullptr, nullptr, 512, nullptr, 0, nullptr);
    }
  }

  // pred_adj[b,v,w] = rbuf[b,w,v]
  adj_out_kernel<<<256, 256, 0, stream>>>(rbuf, out);
  // x[b,v,:] = sum_w sigmoid(rbuf[b,w,v]) * M[b,:,v,w]
  msum_kernel<<<1024, 512, 0, stream>>>(rbuf, Mb, xb);
  // GRU gates
  gemm_bt<3, false><<<dim3(12, 8), 256, 0, stream>>>(xb, 512, 0, Wihb, 512, 512, bihb,
      nullptr, nullptr, nullptr, nullptr, gi, 1536, nullptr, 0, nullptr);
  gemm_bt<3, false><<<dim3(12, 8), 256, 0, stream>>>(nfb, 512, 0, Whhb, 512, 512, bhhb,
      nullptr, nullptr, nullptr, nullptr, gh, 1536, nullptr, 0, nullptr);
  gru_kernel<<<2048, 256, 0, stream>>>(gi, gh, nfb, hn);
  readout_kernel<<<1024, 256, 0, stream>>>(hn, Wr1b, br1b, Wr2b, br2b, out);
}